// Round 7
// baseline (843.034 us; speedup 1.0000x reference)
//
#include <hip/hip_runtime.h>
#include <cstdint>

typedef _Float16 f16;
typedef f16 f16x2 __attribute__((ext_vector_type(2)));
typedef f16 f16x4 __attribute__((ext_vector_type(4)));
typedef f16 f16x8 __attribute__((ext_vector_type(8)));
typedef float f32x4 __attribute__((ext_vector_type(4)));

// problem constants (fixed by harness)
constexpr int D = 768;
constexpr int NTOK = 197;     // tokens per frame (1 cls + 196 spatial)
constexpr int BT = 64;        // B*T
constexpr int ROWS_A = BT * NTOK;      // 12608
constexpr int SEQ = 1569;              // T*H*W + 1
constexpr int ROWS_Y = 8 * SEQ;        // 12552
constexpr int DH = 3072;
constexpr int CW = 2304;               // 3*D
constexpr long Y_ELEMS = (long)ROWS_Y * D;     // 9639936

// async global->LDS, 16B per lane; LDS dest = wave-uniform base + lane*16
__device__ __forceinline__ void gload_lds16(const f16* g, f16* l) {
  __builtin_amdgcn_global_load_lds(
      (const __attribute__((address_space(1))) void*)g,
      (__attribute__((address_space(3))) void*)l, 16, 0, 0);
}

// ------------------------------------------------ weight convert (fused)
constexpr int DD4 = D * D / 4;      // 147456 quads
constexpr int QKV4 = CW * D / 4;    // 442368
constexpr int FC4 = DH * D / 4;     // 589824
constexpr int W2_TOT = QKV4 + DD4 + 2 * FC4;  // 1769472

__global__ __launch_bounds__(256) void cvt_weights(
    const float* __restrict__ wqkv_f, const float* __restrict__ wproj_f,
    const float* __restrict__ wfc1_f, const float* __restrict__ wfc2_f,
    f16* __restrict__ wqkv, f16* __restrict__ wproj,
    f16* __restrict__ wfc1, f16* __restrict__ wfc2) {
  const int i = blockIdx.x * 256 + threadIdx.x;
  const float* src;
  f16* dst;
  int j;
  if (i < QKV4) { src = wqkv_f; dst = wqkv; j = i; }
  else if (i < QKV4 + DD4) { src = wproj_f; dst = wproj; j = i - QKV4; }
  else if (i < QKV4 + DD4 + FC4) { src = wfc1_f; dst = wfc1; j = i - QKV4 - DD4; }
  else if (i < W2_TOT) { src = wfc2_f; dst = wfc2; j = i - QKV4 - DD4 - FC4; }
  else return;
  const float4 v = *(const float4*)(src + (size_t)j * 4);
  f16x4 o = {(f16)v.x, (f16)v.y, (f16)v.z, (f16)v.w};
  *(f16x4*)(dst + (size_t)j * 4) = o;
}

// ------------------- transpose W_mq, W_mk (768x768 f32) -> f16 transposed
__global__ __launch_bounds__(256) void transpose2_f16(
    const float* __restrict__ wq, const float* __restrict__ wk,
    f16* __restrict__ wqT, f16* __restrict__ wkT) {
  __shared__ float tile[32][33];
  const int bid = blockIdx.x;
  const int bx = bid % 24, by = (bid / 24) % 24, z = bid / 576;
  const float* src = z ? wk : wq;
  f16* dst = z ? wkT : wqT;
  const int tx = threadIdx.x & 31, ty4 = (threadIdx.x >> 5) * 4;
#pragma unroll
  for (int r = 0; r < 4; r++)
    tile[ty4 + r][tx] = src[(size_t)(by * 32 + ty4 + r) * D + bx * 32 + tx];
  __syncthreads();
#pragma unroll
  for (int r = 0; r < 4; r++)
    dst[(size_t)(bx * 32 + ty4 + r) * D + by * 32 + tx] = (f16)tile[tx][ty4 + r];
}

// ---------------- rq = W_mq^T b_mk, rk = W_mk^T b_mq, c0 = b_mq.b_mk
__global__ __launch_bounds__(256) void weight_prep(
    const float* __restrict__ wq, const float* __restrict__ wk,
    const float* __restrict__ bq, const float* __restrict__ bk,
    float* __restrict__ rq, float* __restrict__ rk, float* __restrict__ beta) {
  const int tid = blockIdx.x * 256 + threadIdx.x;   // grid 6 -> [0,1536)
  if (tid < D) {
    float s = 0.f;
    for (int k = 0; k < D; k++) s += wq[(size_t)k * D + tid] * bk[k];
    rq[tid] = s;
  } else if (tid < 2 * D) {
    const int i = tid - D;
    float s = 0.f;
    for (int k = 0; k < D; k++) s += wk[(size_t)k * D + i] * bq[k];
    rk[i] = s;
  }
  if (blockIdx.x == 0 && threadIdx.x < 64) {
    float c = 0.f;
    for (int k = threadIdx.x; k < D; k += 64) c += bq[k] * bk[k];
    for (int off = 32; off; off >>= 1) c += __shfl_xor(c, off);
    if (threadIdx.x == 0) beta[ROWS_A] = c;   // c0 parked after beta[0..ROWS_A)
  }
}

// ---------- build xt (f16) + xn = LN(xt); also alpha = xt.rq, beta = xt.rk
__global__ __launch_bounds__(192) void build_xt_xn(
    const float* __restrict__ x, const float* __restrict__ g1,
    const float* __restrict__ be1, const float* __restrict__ rq,
    const float* __restrict__ rk, f16* __restrict__ xt, f16* __restrict__ xn,
    float* __restrict__ alpha, float* __restrict__ beta) {
  const int rid = blockIdx.x;          // 0..12607
  const int bt = rid / NTOK, n = rid % NTOK;
  const int b = bt >> 3, t = bt & 7;
  const int src = (n == 0) ? b * SEQ : b * SEQ + 1 + (n - 1) * 8 + t;
  const int tid = threadIdx.x, d0 = tid * 4;
  const float4 v = *(const float4*)(x + (size_t)src * D + d0);
  const float4 rqv = *(const float4*)(rq + d0);
  const float4 rkv = *(const float4*)(rk + d0);
  float s = v.x + v.y + v.z + v.w;
  float q = v.x * v.x + v.y * v.y + v.z * v.z + v.w * v.w;
  float a = v.x * rqv.x + v.y * rqv.y + v.z * rqv.z + v.w * rqv.w;
  float bb = v.x * rkv.x + v.y * rkv.y + v.z * rkv.z + v.w * rkv.w;
  const int lane = tid & 63, wv = tid >> 6;
  for (int off = 32; off; off >>= 1) {
    s += __shfl_xor(s, off);
    q += __shfl_xor(q, off);
    a += __shfl_xor(a, off);
    bb += __shfl_xor(bb, off);
  }
  __shared__ float red[4][3];
  if (lane == 0) { red[0][wv] = s; red[1][wv] = q; red[2][wv] = a; red[3][wv] = bb; }
  __syncthreads();
  s = red[0][0] + red[0][1] + red[0][2];
  q = red[1][0] + red[1][1] + red[1][2];
  if (tid == 0) {
    alpha[rid] = red[2][0] + red[2][1] + red[2][2];
    beta[rid] = red[3][0] + red[3][1] + red[3][2];
  }
  const float mean = s * (1.f / 768.f);
  const float var = q * (1.f / 768.f) - mean * mean;
  const float rs = rsqrtf(var + 1e-5f);
  const size_t ob = (size_t)rid * D + d0;
  f16x4 xo = {(f16)v.x, (f16)v.y, (f16)v.z, (f16)v.w};
  *(f16x4*)(xt + ob) = xo;
  const float4 gv = *(const float4*)(g1 + d0);
  const float4 bv = *(const float4*)(be1 + d0);
  f16x4 no = {(f16)((v.x - mean) * rs * gv.x + bv.x),
              (f16)((v.y - mean) * rs * gv.y + bv.y),
              (f16)((v.z - mean) * rs * gv.z + bv.z),
              (f16)((v.w - mean) * rs * gv.w + bv.w)};
  *(f16x4*)(xn + ob) = no;
}

// ---------------------------------------------------------------- GEMM
// C[M,N] = A[M,K] @ B[N,K]^T  (+ epilogue).  A,B f16 row-major.
// R0-proven K-loop (2-buffer, stage-before-compute, __syncthreads).
// R7 model (validated against R0/R4/R6 counters): these GEMMs sit at the
// global->LDS staging roofline (~6.5 TB/s aggregate; fc2 891 MB -> 137 us
// matches measurement).  The only winning lever is fewer staged bytes:
// staging ~ (1/BM + 1/BN).  BNT=256 cuts the factor x0.75 for N>=2304
// GEMMs (fc1, qkv) where the grid stays balanced.  N=768 GEMMs stay 128^2
// (BN=256 gives a 297-block degenerate grid; BM/BN=64 adds bytes or MFMA
// starvation -- measured regressions R4/R6).
constexpr int EPI_F16 = 0;            // Ch = acc
constexpr int EPI_F16_BIAS = 1;       // Ch = acc + bias
constexpr int EPI_SIG = 2;            // Cf = sigmoid(acc + alpha+beta+c0)
constexpr int EPI_F16_BIAS_GELU = 3;  // Ch = gelu(acc + bias)
constexpr int EPI_F32_BIAS_RES = 4;   // Cf = acc + bias + Res

template <int EPI, int BNT = 128, int MINW = 3>
__global__ __launch_bounds__(256, MINW) void gemm_f16(
    const f16* __restrict__ A, const f16* __restrict__ B,
    const float* __restrict__ bias, float* __restrict__ Cf,
    f16* __restrict__ Ch, const float* __restrict__ Res, int M, int N, int K,
    int lda, int ldb, int ldc, long sA, long sB, long sC) {
  constexpr int BM = 128, BK = 32;
  constexpr int NJ = BNT / 32;        // j-fragments per wave (4 or 8)
  __shared__ f16 As[2][BM][BK];       // 16 KB
  __shared__ f16 Bs[2][BNT][BK];      // 16 or 32 KB
  const int tid = threadIdx.x;
  const int bm = blockIdx.y * BM, bn = blockIdx.x * BNT;
  const int z = blockIdx.z;
  A += (size_t)z * sA;
  B += (size_t)z * sB;
  const int lane = tid & 63, wave = tid >> 6;
  const int wm = (wave >> 1) * 64, wn = (wave & 1) * (BNT / 2);
  const int l15 = lane & 15, quad = lane >> 4;

  // staging: one wave-instr covers 16 rows (64 lanes x 16 B = 16 x 64 B).
  // A: waves stage row-groups {w, w+4}.  B: {w, w+4} (+ {w+8, w+12} @256).
  const int gr = lane >> 2;         // row within group
  const int gc = (lane & 3) * 8;    // f16 col offset within row
  int a_row0 = bm + wave * 16 + gr;        if (a_row0 >= M) a_row0 = M - 1;
  int a_row1 = bm + (wave + 4) * 16 + gr;  if (a_row1 >= M) a_row1 = M - 1;
  int b_row0 = bn + wave * 16 + gr;        if (b_row0 >= N) b_row0 = N - 1;
  int b_row1 = bn + (wave + 4) * 16 + gr;  if (b_row1 >= N) b_row1 = N - 1;
  int b_row2 = bn + (wave + 8) * 16 + gr;  if (b_row2 >= N) b_row2 = N - 1;
  int b_row3 = bn + (wave + 12) * 16 + gr; if (b_row3 >= N) b_row3 = N - 1;
  const f16* ap0 = A + (size_t)a_row0 * lda + gc;
  const f16* ap1 = A + (size_t)a_row1 * lda + gc;
  const f16* bp0 = B + (size_t)b_row0 * ldb + gc;
  const f16* bp1 = B + (size_t)b_row1 * ldb + gc;
  const f16* bp2 = B + (size_t)b_row2 * ldb + gc;
  const f16* bp3 = B + (size_t)b_row3 * ldb + gc;

  f32x4 acc[4][NJ] = {};

  auto stage = [&](int buf, int k) {
    gload_lds16(ap0 + k, &As[buf][wave * 16][0]);
    gload_lds16(ap1 + k, &As[buf][(wave + 4) * 16][0]);
    gload_lds16(bp0 + k, &Bs[buf][wave * 16][0]);
    gload_lds16(bp1 + k, &Bs[buf][(wave + 4) * 16][0]);
    if constexpr (BNT == 256) {
      gload_lds16(bp2 + k, &Bs[buf][(wave + 8) * 16][0]);
      gload_lds16(bp3 + k, &Bs[buf][(wave + 12) * 16][0]);
    }
  };
  auto compute = [&](int buf) {
    f16x8 af[4], bf[NJ];
#pragma unroll
    for (int i = 0; i < 4; i++)
      af[i] = *(const f16x8*)&As[buf][wm + i * 16 + l15][quad * 8];
#pragma unroll
    for (int j = 0; j < NJ; j++)
      bf[j] = *(const f16x8*)&Bs[buf][wn + j * 16 + l15][quad * 8];
#pragma unroll
    for (int i = 0; i < 4; i++)
#pragma unroll
      for (int j = 0; j < NJ; j++)
        acc[i][j] =
            __builtin_amdgcn_mfma_f32_16x16x32_f16(af[i], bf[j], acc[i][j], 0, 0, 0);
  };

  stage(0, 0);
  __syncthreads();
  // K/BK is even for all our shapes (768/32=24, 3072/32=96)
  for (int kt = 0; kt < K; kt += 2 * BK) {
    stage(1, kt + BK);            // prefetch while computing buf0
    compute(0);
    __syncthreads();              // drains prefetch DMA + buf0 reads
    if (kt + 2 * BK < K) stage(0, kt + 2 * BK);
    compute(1);
    __syncthreads();
  }

#pragma unroll
  for (int i = 0; i < 4; i++) {
#pragma unroll
    for (int j = 0; j < NJ; j++) {
      const int col = bn + wn + j * 16 + l15;
      if (col >= N) continue;
#pragma unroll
      for (int r = 0; r < 4; r++) {
        const int row = bm + wm + i * 16 + quad * 4 + r;
        if (row >= M) continue;
        float v = acc[i][j][r];
        const size_t ci = (size_t)z * sC + (size_t)row * ldc + col;
        if constexpr (EPI == EPI_F16) {
          Ch[ci] = (f16)v;
        } else if constexpr (EPI == EPI_F16_BIAS) {
          Ch[ci] = (f16)(v + bias[col]);
        } else if constexpr (EPI == EPI_SIG) {
          // bias = alpha (z*NTOK+row), Res = beta (z*NTOK+col), c0 at Res[ROWS_A]
          v += bias[(size_t)z * NTOK + row] + Res[(size_t)z * NTOK + col] +
               Res[ROWS_A];
          if (row == 0 && col == 0) v = 100.f;
          Cf[ci] = 1.f / (1.f + __expf(-v));
        } else if constexpr (EPI == EPI_F16_BIAS_GELU) {
          // tanh-approx gelu via one v_exp_f32 (validated R3-R5, err ~3e-4)
          const float u = v + bias[col];
          const float t = u * (0.79788456f + 0.0356774081f * u * u);
          const float e = __expf(2.f * t);
          Ch[ci] = (f16)(u * (e / (e + 1.f)));
        } else if constexpr (EPI == EPI_F32_BIAS_RES) {
          Cf[ci] = v + bias[col] + Res[ci];
        }
      }
    }
  }
}

// ---------------------------------------------------------------- attention
// MFMA attention. One block per (bt, head); 4 waves, each wave owns 16-query
// tiles. S = Q K^T held in registers (13 x f32x4), register softmax + lm gate,
// P converted C-layout -> A-layout via per-wave 32-col LDS chunk, PV via MFMA.
__global__ __launch_bounds__(256, 2) void attn_kernel(
    const f16* __restrict__ qkv, const float* __restrict__ lm,
    f16* __restrict__ o) {
  __shared__ f16 Ks[208][72];     // 29952 B  (stride 144 B = 36 dwords)
  __shared__ f16 Vt[64][232];     // 29696 B  (stride 464 B = 116 dwords)
  __shared__ f16 Ps[4][16][40];   //  5120 B  (per-wave P chunk, 80 B = 20 dw)
  const int bh = blockIdx.x;
  const int bt = bh / 12, h = bh % 12;
  const int tid = threadIdx.x, lane = tid & 63, w = tid >> 6;
  const int l15 = lane & 15, quad = lane >> 4;
  const size_t base = (size_t)bt * NTOK * CW + (size_t)h * 64;

  // ---- stage K rows 0..196 (zeros for 197..207)
  for (int idx = tid; idx < 208 * 8; idx += 256) {
    const int r = idx >> 3, c = (idx & 7) * 8;
    f16x8 kv = {};
    if (r < NTOK) kv = *(const f16x8*)(qkv + base + (size_t)r * CW + 768 + c);
    *(f16x8*)&Ks[r][c] = kv;
  }
  // ---- stage V transposed: Vt[d][m]
  for (int cb = 0; cb < 8; cb++) {
    const int r = tid;
    if (r < NTOK) {
      const f16x8 vv = *(const f16x8*)(qkv + base + (size_t)r * CW + 1536 + cb * 8);
#pragma unroll
      for (int j = 0; j < 8; j++) Vt[cb * 8 + j][r] = vv[j];
    }
  }
  // zero-fill Vt cols 197..231 (prevents 0*NaN in PV MFMA)
  for (int idx = tid; idx < 64 * 35; idx += 256) {
    const int d = idx / 35, m = NTOK + idx % 35;
    Vt[d][m] = (f16)0.f;
  }
  __syncthreads();

  for (int nt = w; nt < 13; nt += 4) {
    // ---- S = Q K^T
    const int nq = nt * 16 + l15;
    const f16* qrow = qkv + base + (size_t)nq * CW;
    const f16x8 aq0 = *(const f16x8*)(qrow + quad * 8);
    const f16x8 aq1 = *(const f16x8*)(qrow + 32 + quad * 8);
    f32x4 S[13];
#pragma unroll
    for (int t = 0; t < 13; t++) {
      const f16x8 bk0 = *(const f16x8*)&Ks[t * 16 + l15][quad * 8];
      const f16x8 bk1 = *(const f16x8*)&Ks[t * 16 + l15][32 + quad * 8];
      f32x4 s = {};
      s = __builtin_amdgcn_mfma_f32_16x16x32_f16(aq0, bk0, s, 0, 0, 0);
      s = __builtin_amdgcn_mfma_f32_16x16x32_f16(aq1, bk1, s, 0, 0, 0);
      S[t] = s;
    }
    // ---- register softmax over m (rows n_loc = quad*4+r, col m = t*16+l15)
    float mx[4] = {-3e38f, -3e38f, -3e38f, -3e38f};
#pragma unroll
    for (int t = 0; t < 13; t++) {
      const int m = t * 16 + l15;
#pragma unroll
      for (int r = 0; r < 4; r++) {
        float v = (m < NTOK) ? S[t][r] * 0.125f : -1e30f;
        S[t][r] = v;
        mx[r] = fmaxf(mx[r], v);
      }
    }
#pragma unroll
    for (int off = 1; off < 16; off <<= 1)
#pragma unroll
      for (int r = 0; r < 4; r++) mx[r] = fmaxf(mx[r], __shfl_xor(mx[r], off));
    float den[4] = {0.f, 0.f, 0.f, 0.f};
#pragma unroll
    for (int t = 0; t < 13; t++)
#pragma unroll
      for (int r = 0; r < 4; r++) {
        const float e = __expf(S[t][r] - mx[r]);
        S[t][r] = e;
        den[r] += e;
      }
#pragma unroll
    for (int off = 1; off < 16; off <<= 1)
#pragma unroll
      for (int r = 0; r < 4; r++) den[r] += __shfl_xor(den[r], off);
    float inv[4];
#pragma unroll
    for (int r = 0; r < 4; r++) inv[r] = 1.f / den[r];
    // ---- gate with lm (guard both dims: lm buffer is exactly 197x197)
#pragma unroll
    for (int t = 0; t < 13; t++) {
      const int m = t * 16 + l15;
#pragma unroll
      for (int r = 0; r < 4; r++) {
        const int nrow = nt * 16 + quad * 4 + r;
        float g = 0.f;
        if (m < NTOK && nrow < NTOK)
          g = lm[((size_t)bt * NTOK + nrow) * NTOK + m];
        S[t][r] *= inv[r] * g;
      }
    }
    // ---- PV: chunk P (C-layout) through per-wave LDS to A-layout, MFMA
    f32x4 O[4] = {};
    for (int c = 0; c < 7; c++) {
      __builtin_amdgcn_wave_barrier();  // keep chunk writes after prior reads
#pragma unroll
      for (int tt = 0; tt < 2; tt++) {
        const int t = 2 * c + tt;
#pragma unroll
        for (int r = 0; r < 4; r++) {
          const f16 pv = (t < 13) ? (f16)S[t][r] : (f16)0.f;
          Ps[w][quad * 4 + r][tt * 16 + l15] = pv;
        }
      }
      __builtin_amdgcn_wave_barrier();  // writes before reads (in-order DS pipe)
      const f16x8 ap = *(const f16x8*)&Ps[w][l15][quad * 8];
#pragma unroll
      for (int dt = 0; dt < 4; dt++) {
        const f16x8 bv = *(const f16x8*)&Vt[dt * 16 + l15][c * 32 + quad * 8];
        O[dt] = __builtin_amdgcn_mfma_f32_16x16x32_f16(ap, bv, O[dt], 0, 0, 0);
      }
    }
    // ---- store O (C-layout: row n_loc = quad*4+r, col d = dt*16+l15)
#pragma unroll
    for (int dt = 0; dt < 4; dt++)
#pragma unroll
      for (int r = 0; r < 4; r++) {
        const int nrow = nt * 16 + quad * 4 + r;
        if (nrow < NTOK)
          o[((size_t)bt * NTOK + nrow) * D + h * 64 + dt * 16 + l15] =
              (f16)O[dt][r];
      }
  }
}

// ---------------------------------- y = x + scatter(proj_out); yn = LN(y)
__global__ __launch_bounds__(192) void scatter_y_ln(
    const float* __restrict__ x, const f16* __restrict__ po,
    const float* __restrict__ g2, const float* __restrict__ be2,
    float* __restrict__ y, f16* __restrict__ yn) {
  const int rid = blockIdx.x;  // 0..12551
  const int b = rid / SEQ, pos = rid % SEQ;
  const int tid = threadIdx.x, d0 = tid * 4;
  float4 v = *(const float4*)(x + (size_t)rid * D + d0);
  if (pos == 0) {
    float ax = 0, ay = 0, az = 0, aw = 0;
    for (int t = 0; t < 8; t++) {
      const f16x4 p = *(const f16x4*)(po + ((size_t)(b * 8 + t) * NTOK) * D + d0);
      ax += (float)p[0]; ay += (float)p[1]; az += (float)p[2]; aw += (float)p[3];
    }
    v.x += ax * 0.125f; v.y += ay * 0.125f; v.z += az * 0.125f; v.w += aw * 0.125f;
  } else {
    const int hw = (pos - 1) >> 3, t = (pos - 1) & 7;
    const f16x4 p =
        *(const f16x4*)(po + ((size_t)((b * 8 + t) * NTOK + 1 + hw)) * D + d0);
    v.x += (float)p[0]; v.y += (float)p[1]; v.z += (float)p[2]; v.w += (float)p[3];
  }
  *(float4*)(y + (size_t)rid * D + d0) = v;
  float s = v.x + v.y + v.z + v.w;
  float q = v.x * v.x + v.y * v.y + v.z * v.z + v.w * v.w;
  const int lane = tid & 63, wv = tid >> 6;
  for (int off = 32; off; off >>= 1) {
    s += __shfl_xor(s, off);
    q += __shfl_xor(q, off);
  }
  __shared__ float red[2][3];
  if (lane == 0) { red[0][wv] = s; red[1][wv] = q; }
  __syncthreads();
  s = red[0][0] + red[0][1] + red[0][2];
  q = red[1][0] + red[1][1] + red[1][2];
  const float mean = s * (1.f / 768.f);
  const float var = q * (1.f / 768.f) - mean * mean;
  const float rs = rsqrtf(var + 1e-5f);
  const float4 gv = *(const float4*)(g2 + d0);
  const float4 bv = *(const float4*)(be2 + d0);
  f16x4 no = {(f16)((v.x - mean) * rs * gv.x + bv.x),
              (f16)((v.y - mean) * rs * gv.y + bv.y),
              (f16)((v.z - mean) * rs * gv.z + bv.z),
              (f16)((v.w - mean) * rs * gv.w + bv.w)};
  *(f16x4*)(yn + (size_t)rid * D + d0) = no;
}

// ---------------------------------------------------------------- launch
extern "C" void kernel_launch(void* const* d_in, const int* in_sizes, int n_in,
                              void* d_out, int out_size, void* d_ws,
                              size_t ws_size, hipStream_t stream) {
  const float* x = (const float*)d_in[0];
  const float* W_mq = (const float*)d_in[1];
  const float* b_mq = (const float*)d_in[2];
  const float* W_mk = (const float*)d_in[3];
  const float* b_mk = (const float*)d_in[4];
  const float* g1 = (const float*)d_in[5];
  const float* be1 = (const float*)d_in[6];
  const float* W_qkv = (const float*)d_in[7];
  const float* W_proj = (const float*)d_in[8];
  const float* b_proj = (const float*)d_in[9];
  const float* g2 = (const float*)d_in[10];
  const float* be2 = (const float*)d_in[11];
  const float* W_fc1 = (const float*)d_in[12];
  const float* b_fc1 = (const float*)d_in[13];
  const float* W_fc2 = (const float*)d_in[14];
  const float* b_fc2 = (const float*)d_in[15];

  char* ws = (char*)d_ws;
  size_t off = 0;
  auto alloc = [&](size_t bytes) {
    size_t o = off;
    off = (off + bytes + 255) & ~(size_t)255;
    return o;
  };
  const size_t o_wqT = alloc((size_t)D * D * 2);        // W_mq^T f16
  const size_t o_wkT = alloc((size_t)D * D * 2);        // W_mk^T f16
  const size_t o_wct = alloc((size_t)D * D * 2);        // WcT = Wk^T Wq (f16)
  const size_t o_rq = alloc((size_t)D * 4);
  const size_t o_rk = alloc((size_t)D * 4);
  const size_t o_alpha = alloc((size_t)(ROWS_A + 1) * 4);
  const size_t o_beta = alloc((size_t)(ROWS_A + 1) * 4); // c0 at [ROWS_A]
  const size_t o_wqkv = alloc((size_t)CW * D * 2);
  const size_t o_wproj = alloc((size_t)D * D * 2);
  const size_t o_wfc1 = alloc((size_t)DH * D * 2);
  const size_t o_wfc2 = alloc((size_t)D * DH * 2);
  const size_t o_xt = alloc((size_t)ROWS_A * D * 2);
  const size_t o_xn = alloc((size_t)ROWS_A * D * 2);
  const size_t o_big = alloc((size_t)ROWS_A * CW * 2);  // qkv, later h
  const size_t o_po = alloc((size_t)ROWS_A * D * 2);    // t, later proj out
  // aliases (lifetimes disjoint):
  const size_t o_t = o_po;      // t = xt@WcT; dead after lm GEMM (pre-attn)
  const size_t o_qkv = o_big;   // qkv; dead after attn
  const size_t o_o = o_xn;      // attn out after xn dead
  const size_t o_yn = o_xt;     // yn after xt dead
  const size_t o_h = o_big;     // h (77.4 MB) spans big+po after both dead

  f16* wqT = (f16*)(ws + o_wqT);
  f16* wkT = (f16*)(ws + o_wkT);
  f16* wct = (f16*)(ws + o_wct);
  float* rq = (float*)(ws + o_rq);
  float* rk = (float*)(ws + o_rk);
  float* alpha = (float*)(ws + o_alpha);
  float* beta = (float*)(ws + o_beta);
  f16* wqkv = (f16*)(ws + o_wqkv);
  f16* wproj = (f16*)(ws + o_wproj);
  f16* wfc1 = (f16*)(ws + o_wfc1);
  f16* wfc2 = (f16*)(ws + o_wfc2);
  f16* xt = (f16*)(ws + o_xt);
  f16* xn = (f16*)(ws + o_xn);
  f16* tmat = (f16*)(ws + o_t);
  f16* qkv = (f16*)(ws + o_qkv);
  f16* oatt = (f16*)(ws + o_o);
  f16* po = (f16*)(ws + o_po);
  f16* yn = (f16*)(ws + o_yn);
  f16* h = (f16*)(ws + o_h);

  float* y_out = (float*)d_out;
  float* lm_out = (float*)d_out + Y_ELEMS;

  const dim3 blk(256);
  cvt_weights<<<dim3((W2_TOT + 255) / 256), blk, 0, stream>>>(
      W_qkv, W_proj, W_fc1, W_fc2, wqkv, wproj, wfc1, wfc2);
  transpose2_f16<<<dim3(24 * 24 * 2), blk, 0, stream>>>(W_mq, W_mk, wqT, wkT);
  weight_prep<<<dim3(6), blk, 0, stream>>>(W_mq, W_mk, b_mq, b_mk, rq, rk, beta);

  build_xt_xn<<<dim3(ROWS_A), dim3(192), 0, stream>>>(x, g1, be1, rq, rk, xt,
                                                      xn, alpha, beta);

  auto grd = [](int N_, int M_, int Z_) {
    return dim3((N_ + 127) / 128, (M_ + 127) / 128, Z_);
  };
  auto grd256 = [](int N_, int M_) {
    return dim3((N_ + 255) / 256, (M_ + 127) / 128, 1);
  };
  // WcT = Wk^T @ Wq  (C[m,n] = sum_k WkT[m,k] WqT[n,k] = Wc[n,m])
  gemm_f16<EPI_F16><<<grd(D, D, 1), blk, 0, stream>>>(
      wkT, wqT, nullptr, nullptr, wct, nullptr, D, D, D, D, D, D, 0, 0, 0);
  // t = xt @ Wc  (t[n,j] = sum_i xt[n,i] WcT[j,i])
  gemm_f16<EPI_F16><<<grd(D, ROWS_A, 1), blk, 0, stream>>>(
      xt, wct, nullptr, nullptr, tmat, nullptr, ROWS_A, D, D, D, D, D,
      0, 0, 0);
  // lm = sigmoid(t xt^T + alpha[n] + beta[m] + c0) batched -> d_out
  gemm_f16<EPI_SIG><<<grd(NTOK, NTOK, BT), blk, 0, stream>>>(
      tmat, xt, alpha, lm_out, nullptr, beta, NTOK, NTOK, D, D, D, NTOK,
      (long)NTOK * D, (long)NTOK * D, (long)NTOK * NTOK);
  // qkv = xn @ W_qkv^T  (no bias): BN=256 -> staging x0.75 (684->513 MB)
  gemm_f16<EPI_F16, 256, 2><<<grd256(CW, ROWS_A), blk, 0, stream>>>(
      xn, wqkv, nullptr, nullptr, qkv, nullptr, ROWS_A, CW, D, D, D, CW,
      0, 0, 0);
  // attention
  attn_kernel<<<dim3(BT * 12), blk, 0, stream>>>(qkv, lm_out, oatt);
  // proj (f16 out + bias)
  gemm_f16<EPI_F16_BIAS><<<grd(D, ROWS_A, 1), blk, 0, stream>>>(
      oatt, wproj, b_proj, nullptr, po, nullptr, ROWS_A, D, D, D, D, D,
      0, 0, 0);
  // y = x + scatter(po); yn = LN(y)
  scatter_y_ln<<<dim3(ROWS_Y), dim3(192), 0, stream>>>(x, po, g2, be2, y_out, yn);
  // fc1 + gelu: BN=256 -> staging x0.75 (912->684 MB)
  gemm_f16<EPI_F16_BIAS_GELU, 256, 2><<<grd256(DH, ROWS_Y), blk, 0, stream>>>(
      yn, wfc1, b_fc1, nullptr, h, nullptr, ROWS_Y, DH, D, D, D, DH, 0, 0, 0);
  // fc2 + bias + residual -> final y (128^2: N=768 grid needs the balance)
  gemm_f16<EPI_F32_BIAS_RES><<<grd(D, ROWS_Y, 1), blk, 0, stream>>>(
      h, wfc2, b_fc2, y_out, nullptr, y_out, ROWS_Y, D, DH, DH, DH, D,
      0, 0, 0);
  (void)in_sizes; (void)n_in; (void)out_size; (void)ws_size;
}

// Round 8
// 617.553 us; speedup vs baseline: 1.3651x; 1.3651x over previous
//
#include <hip/hip_runtime.h>
#include <cstdint>

typedef _Float16 f16;
typedef f16 f16x2 __attribute__((ext_vector_type(2)));
typedef f16 f16x4 __attribute__((ext_vector_type(4)));
typedef f16 f16x8 __attribute__((ext_vector_type(8)));
typedef float f32x4 __attribute__((ext_vector_type(4)));

// problem constants (fixed by harness)
constexpr int D = 768;
constexpr int NTOK = 197;     // tokens per frame (1 cls + 196 spatial)
constexpr int BT = 64;        // B*T
constexpr int ROWS_A = BT * NTOK;      // 12608
constexpr int SEQ = 1569;              // T*H*W + 1
constexpr int ROWS_Y = 8 * SEQ;        // 12552
constexpr int DH = 3072;
constexpr int CW = 2304;               // 3*D
constexpr long Y_ELEMS = (long)ROWS_Y * D;     // 9639936

// async global->LDS, 16B per lane; LDS dest = wave-uniform base + lane*16
__device__ __forceinline__ void gload_lds16(const f16* g, f16* l) {
  __builtin_amdgcn_global_load_lds(
      (const __attribute__((address_space(1))) void*)g,
      (__attribute__((address_space(3))) void*)l, 16, 0, 0);
}

// ------------------------------------------------ weight convert (fused)
constexpr int DD4 = D * D / 4;      // 147456 quads
constexpr int QKV4 = CW * D / 4;    // 442368
constexpr int FC4 = DH * D / 4;     // 589824
constexpr int WQ_TOT = 3 * DD4 + QKV4 + 2 * FC4;  // 2064384

__global__ __launch_bounds__(256) void cvt_weights(
    const float* __restrict__ wmq_f, const float* __restrict__ wmk_f,
    const float* __restrict__ wqkv_f, const float* __restrict__ wproj_f,
    const float* __restrict__ wfc1_f, const float* __restrict__ wfc2_f,
    f16* __restrict__ wmqk, f16* __restrict__ wqkv, f16* __restrict__ wproj,
    f16* __restrict__ wfc1, f16* __restrict__ wfc2) {
  const int i = blockIdx.x * 256 + threadIdx.x;
  const float* src;
  f16* dst;
  int j;
  if (i < DD4) { src = wmq_f; dst = wmqk; j = i; }
  else if (i < 2 * DD4) { src = wmk_f; dst = wmqk + (size_t)D * D; j = i - DD4; }
  else if (i < 2 * DD4 + QKV4) { src = wqkv_f; dst = wqkv; j = i - 2 * DD4; }
  else if (i < 3 * DD4 + QKV4) { src = wproj_f; dst = wproj; j = i - 2 * DD4 - QKV4; }
  else if (i < 3 * DD4 + QKV4 + FC4) { src = wfc1_f; dst = wfc1; j = i - 3 * DD4 - QKV4; }
  else if (i < WQ_TOT) { src = wfc2_f; dst = wfc2; j = i - 3 * DD4 - QKV4 - FC4; }
  else return;
  const float4 v = *(const float4*)(src + (size_t)j * 4);
  f16x4 o = {(f16)v.x, (f16)v.y, (f16)v.z, (f16)v.w};
  *(f16x4*)(dst + (size_t)j * 4) = o;
}

// concat two f32 vectors of length n -> out[0:n]=a, out[n:2n]=b
__global__ __launch_bounds__(256) void concat2_f32(const float* __restrict__ a,
                                                   const float* __restrict__ b,
                                                   float* __restrict__ o, int n) {
  int i = blockIdx.x * 256 + threadIdx.x;
  if (i < n) o[i] = a[i];
  else if (i < 2 * n) o[i] = b[i - n];
}

// --------------------------------------------- build xt (f16) + xn = LN(xt)
// one block per (bt, n) row; 192 threads x 4 floats = 768
__global__ __launch_bounds__(192) void build_xt_xn(
    const float* __restrict__ x, const float* __restrict__ g1,
    const float* __restrict__ be1, f16* __restrict__ xt, f16* __restrict__ xn) {
  const int rid = blockIdx.x;          // 0..12607
  const int bt = rid / NTOK, n = rid % NTOK;
  const int b = bt >> 3, t = bt & 7;
  const int src = (n == 0) ? b * SEQ : b * SEQ + 1 + (n - 1) * 8 + t;
  const int tid = threadIdx.x, d0 = tid * 4;
  const float4 v = *(const float4*)(x + (size_t)src * D + d0);
  float s = v.x + v.y + v.z + v.w;
  float q = v.x * v.x + v.y * v.y + v.z * v.z + v.w * v.w;
  const int lane = tid & 63, wv = tid >> 6;
  for (int off = 32; off; off >>= 1) {
    s += __shfl_xor(s, off);
    q += __shfl_xor(q, off);
  }
  __shared__ float red[2][3];
  if (lane == 0) { red[0][wv] = s; red[1][wv] = q; }
  __syncthreads();
  s = red[0][0] + red[0][1] + red[0][2];
  q = red[1][0] + red[1][1] + red[1][2];
  const float mean = s * (1.f / 768.f);
  const float var = q * (1.f / 768.f) - mean * mean;
  const float rs = rsqrtf(var + 1e-5f);
  const size_t ob = (size_t)rid * D + d0;
  f16x4 xo = {(f16)v.x, (f16)v.y, (f16)v.z, (f16)v.w};
  *(f16x4*)(xt + ob) = xo;
  const float4 gv = *(const float4*)(g1 + d0);
  const float4 bv = *(const float4*)(be1 + d0);
  f16x4 no = {(f16)((v.x - mean) * rs * gv.x + bv.x),
              (f16)((v.y - mean) * rs * gv.y + bv.y),
              (f16)((v.z - mean) * rs * gv.z + bv.z),
              (f16)((v.w - mean) * rs * gv.w + bv.w)};
  *(f16x4*)(xn + ob) = no;
}

// ---------------------------------------------------------------- GEMM
// C[M,N] = A[M,K] @ B[N,K]^T  (+ epilogue).  A,B f16 row-major.
// EXACT R0-proven structure (128^2 tile, BK=32, 2-buffer, stage-before-
// compute, __syncthreads).  R2/R3/R5/R7 established: counted-vmcnt
// pipelines, atomic split-K, and any config that drops below ~3 resident
// blocks/CU (64KB LDS, 200-VGPR acc) all regress -- the kernel is
// stage-LATENCY-bound, hidden only by co-resident-block overlap.
// R8 lever: XCD-aware chunked block swizzle (T1, m204 bijective form).
// Default round-robin dispatch scatters the blocks sharing an A-row-panel
// across 8 XCD L2s (fc2 FETCH 255 MB vs 77 MB panel = ~3.3x HBM re-fetch,
// stage misses at ~900cy).  Chunk-mapping gives each XCD a contiguous run
// of M-rows: A-tiles reused ~6x from its own L2 (~200cy stage latency).
constexpr int EPI_F16 = 0;            // Ch = acc
constexpr int EPI_F16_BIAS = 1;       // Ch = acc + bias
constexpr int EPI_SIG = 2;            // Cf = sigmoid(acc), [0,0] forced to 100
constexpr int EPI_F16_BIAS_GELU = 3;  // Ch = gelu(acc + bias)
constexpr int EPI_F32_BIAS_RES = 4;   // Cf = acc + bias + Res

template <int EPI, bool SWZ = false>
__global__ __launch_bounds__(256, 3) void gemm_f16(
    const f16* __restrict__ A, const f16* __restrict__ B,
    const float* __restrict__ bias, float* __restrict__ Cf,
    f16* __restrict__ Ch, const float* __restrict__ Res, int M, int N, int K,
    int lda, int ldb, int ldc, long sA, long sB, long sC) {
  constexpr int BM = 128, BN = 128, BK = 32;
  __shared__ f16 As[2][BM][BK];   // 2 x 8 KB
  __shared__ f16 Bs[2][BN][BK];   // 2 x 8 KB
  const int tid = threadIdx.x;
  // ---- XCD-aware chunked remap (bijective, m204): hardware round-robins
  // flat id % 8 across XCDs; remap so each XCD owns a CONTIGUOUS range of
  // (M-row, N-col) blocks -> blocks sharing an A panel land on one L2.
  int fid = blockIdx.y * gridDim.x + blockIdx.x;
  if constexpr (SWZ) {
    const int nwg = gridDim.x * gridDim.y;
    const int q = nwg >> 3, r = nwg & 7;
    const int xcd = fid & 7, p = fid >> 3;
    fid = (xcd < r ? xcd * (q + 1) : r * (q + 1) + (xcd - r) * q) + p;
  }
  const int bm = (fid / gridDim.x) * BM, bn = (fid % gridDim.x) * BN;
  const int z = blockIdx.z;
  A += (size_t)z * sA;
  B += (size_t)z * sB;
  const int lane = tid & 63, wave = tid >> 6;
  const int wm = (wave >> 1) * 64, wn = (wave & 1) * 64;
  const int l15 = lane & 15, quad = lane >> 4;

  // staging: one wave-instr covers 16 rows (64 lanes x 16 B = 16 x 64 B).
  // wave w stages row-groups {w, w+4} of A and of B.
  const int gr = lane >> 2;         // row within group
  const int gc = (lane & 3) * 8;    // f16 col offset within row
  int a_row0 = bm + wave * 16 + gr;       if (a_row0 >= M) a_row0 = M - 1;
  int a_row1 = bm + (wave + 4) * 16 + gr; if (a_row1 >= M) a_row1 = M - 1;
  int b_row0 = bn + wave * 16 + gr;       if (b_row0 >= N) b_row0 = N - 1;
  int b_row1 = bn + (wave + 4) * 16 + gr; if (b_row1 >= N) b_row1 = N - 1;
  const f16* ap0 = A + (size_t)a_row0 * lda + gc;
  const f16* ap1 = A + (size_t)a_row1 * lda + gc;
  const f16* bp0 = B + (size_t)b_row0 * ldb + gc;
  const f16* bp1 = B + (size_t)b_row1 * ldb + gc;

  f32x4 acc[4][4] = {};

  auto stage = [&](int buf, int k) {
    gload_lds16(ap0 + k, &As[buf][wave * 16][0]);
    gload_lds16(ap1 + k, &As[buf][(wave + 4) * 16][0]);
    gload_lds16(bp0 + k, &Bs[buf][wave * 16][0]);
    gload_lds16(bp1 + k, &Bs[buf][(wave + 4) * 16][0]);
  };
  auto compute = [&](int buf) {
    f16x8 af[4], bf[4];
#pragma unroll
    for (int i = 0; i < 4; i++) {
      af[i] = *(const f16x8*)&As[buf][wm + i * 16 + l15][quad * 8];
      bf[i] = *(const f16x8*)&Bs[buf][wn + i * 16 + l15][quad * 8];
    }
#pragma unroll
    for (int i = 0; i < 4; i++)
#pragma unroll
      for (int j = 0; j < 4; j++)
        acc[i][j] =
            __builtin_amdgcn_mfma_f32_16x16x32_f16(af[i], bf[j], acc[i][j], 0, 0, 0);
  };

  stage(0, 0);
  __syncthreads();
  // K/BK is even for all our shapes (768/32=24, 3072/32=96)
  for (int kt = 0; kt < K; kt += 2 * BK) {
    stage(1, kt + BK);            // prefetch while computing buf0
    compute(0);
    __syncthreads();              // drains prefetch DMA + buf0 reads
    if (kt + 2 * BK < K) stage(0, kt + 2 * BK);
    compute(1);
    __syncthreads();
  }

#pragma unroll
  for (int i = 0; i < 4; i++) {
#pragma unroll
    for (int j = 0; j < 4; j++) {
      const int col = bn + wn + j * 16 + l15;
      if (col >= N) continue;
#pragma unroll
      for (int r = 0; r < 4; r++) {
        const int row = bm + wm + i * 16 + quad * 4 + r;
        if (row >= M) continue;
        float v = acc[i][j][r];
        const size_t ci = (size_t)z * sC + (size_t)row * ldc + col;
        if constexpr (EPI == EPI_F16) {
          Ch[ci] = (f16)v;
        } else if constexpr (EPI == EPI_F16_BIAS) {
          Ch[ci] = (f16)(v + bias[col]);
        } else if constexpr (EPI == EPI_SIG) {
          if (row == 0 && col == 0) v = 100.f;
          Cf[ci] = 1.f / (1.f + __expf(-v));
        } else if constexpr (EPI == EPI_F16_BIAS_GELU) {
          // tanh-approx gelu via one v_exp_f32 (validated R3-R5, err ~3e-4)
          const float u = v + bias[col];
          const float t = u * (0.79788456f + 0.0356774081f * u * u);
          const float e = __expf(2.f * t);
          Ch[ci] = (f16)(u * (e / (e + 1.f)));
        } else if constexpr (EPI == EPI_F32_BIAS_RES) {
          Cf[ci] = v + bias[col] + Res[ci];
        }
      }
    }
  }
}

// ---------------------------------------------------------------- attention
// MFMA attention. One block per (bt, head); 4 waves, each wave owns 16-query
// tiles. S = Q K^T held in registers (13 x f32x4), register softmax + lm gate,
// P converted C-layout -> A-layout via per-wave 32-col LDS chunk, PV via MFMA.
__global__ __launch_bounds__(256, 2) void attn_kernel(
    const f16* __restrict__ qkv, const float* __restrict__ lm,
    f16* __restrict__ o) {
  __shared__ f16 Ks[208][72];     // 29952 B  (stride 144 B = 36 dwords)
  __shared__ f16 Vt[64][232];     // 29696 B  (stride 464 B = 116 dwords)
  __shared__ f16 Ps[4][16][40];   //  5120 B  (per-wave P chunk, 80 B = 20 dw)
  const int bh = blockIdx.x;
  const int bt = bh / 12, h = bh % 12;
  const int tid = threadIdx.x, lane = tid & 63, w = tid >> 6;
  const int l15 = lane & 15, quad = lane >> 4;
  const size_t base = (size_t)bt * NTOK * CW + (size_t)h * 64;

  // ---- stage K rows 0..196 (zeros for 197..207)
  for (int idx = tid; idx < 208 * 8; idx += 256) {
    const int r = idx >> 3, c = (idx & 7) * 8;
    f16x8 kv = {};
    if (r < NTOK) kv = *(const f16x8*)(qkv + base + (size_t)r * CW + 768 + c);
    *(f16x8*)&Ks[r][c] = kv;
  }
  // ---- stage V transposed: Vt[d][m]
  for (int cb = 0; cb < 8; cb++) {
    const int r = tid;
    if (r < NTOK) {
      const f16x8 vv = *(const f16x8*)(qkv + base + (size_t)r * CW + 1536 + cb * 8);
#pragma unroll
      for (int j = 0; j < 8; j++) Vt[cb * 8 + j][r] = vv[j];
    }
  }
  // zero-fill Vt cols 197..231 (prevents 0*NaN in PV MFMA)
  for (int idx = tid; idx < 64 * 35; idx += 256) {
    const int d = idx / 35, m = NTOK + idx % 35;
    Vt[d][m] = (f16)0.f;
  }
  __syncthreads();

  for (int nt = w; nt < 13; nt += 4) {
    // ---- S = Q K^T
    const int nq = nt * 16 + l15;
    const f16* qrow = qkv + base + (size_t)nq * CW;
    const f16x8 aq0 = *(const f16x8*)(qrow + quad * 8);
    const f16x8 aq1 = *(const f16x8*)(qrow + 32 + quad * 8);
    f32x4 S[13];
#pragma unroll
    for (int t = 0; t < 13; t++) {
      const f16x8 bk0 = *(const f16x8*)&Ks[t * 16 + l15][quad * 8];
      const f16x8 bk1 = *(const f16x8*)&Ks[t * 16 + l15][32 + quad * 8];
      f32x4 s = {};
      s = __builtin_amdgcn_mfma_f32_16x16x32_f16(aq0, bk0, s, 0, 0, 0);
      s = __builtin_amdgcn_mfma_f32_16x16x32_f16(aq1, bk1, s, 0, 0, 0);
      S[t] = s;
    }
    // ---- register softmax over m (rows n_loc = quad*4+r, col m = t*16+l15)
    float mx[4] = {-3e38f, -3e38f, -3e38f, -3e38f};
#pragma unroll
    for (int t = 0; t < 13; t++) {
      const int m = t * 16 + l15;
#pragma unroll
      for (int r = 0; r < 4; r++) {
        float v = (m < NTOK) ? S[t][r] * 0.125f : -1e30f;
        S[t][r] = v;
        mx[r] = fmaxf(mx[r], v);
      }
    }
#pragma unroll
    for (int off = 1; off < 16; off <<= 1)
#pragma unroll
      for (int r = 0; r < 4; r++) mx[r] = fmaxf(mx[r], __shfl_xor(mx[r], off));
    float den[4] = {0.f, 0.f, 0.f, 0.f};
#pragma unroll
    for (int t = 0; t < 13; t++)
#pragma unroll
      for (int r = 0; r < 4; r++) {
        const float e = __expf(S[t][r] - mx[r]);
        S[t][r] = e;
        den[r] += e;
      }
#pragma unroll
    for (int off = 1; off < 16; off <<= 1)
#pragma unroll
      for (int r = 0; r < 4; r++) den[r] += __shfl_xor(den[r], off);
    float inv[4];
#pragma unroll
    for (int r = 0; r < 4; r++) inv[r] = 1.f / den[r];
    // ---- gate with lm (guard both dims: lm buffer is exactly 197x197)
#pragma unroll
    for (int t = 0; t < 13; t++) {
      const int m = t * 16 + l15;
#pragma unroll
      for (int r = 0; r < 4; r++) {
        const int nrow = nt * 16 + quad * 4 + r;
        float g = 0.f;
        if (m < NTOK && nrow < NTOK)
          g = lm[((size_t)bt * NTOK + nrow) * NTOK + m];
        S[t][r] *= inv[r] * g;
      }
    }
    // ---- PV: chunk P (C-layout) through per-wave LDS to A-layout, MFMA
    f32x4 O[4] = {};
    for (int c = 0; c < 7; c++) {
      __builtin_amdgcn_wave_barrier();  // keep chunk writes after prior reads
#pragma unroll
      for (int tt = 0; tt < 2; tt++) {
        const int t = 2 * c + tt;
#pragma unroll
        for (int r = 0; r < 4; r++) {
          const f16 pv = (t < 13) ? (f16)S[t][r] : (f16)0.f;
          Ps[w][quad * 4 + r][tt * 16 + l15] = pv;
        }
      }
      __builtin_amdgcn_wave_barrier();  // writes before reads (in-order DS pipe)
      const f16x8 ap = *(const f16x8*)&Ps[w][l15][quad * 8];
#pragma unroll
      for (int dt = 0; dt < 4; dt++) {
        const f16x8 bv = *(const f16x8*)&Vt[dt * 16 + l15][c * 32 + quad * 8];
        O[dt] = __builtin_amdgcn_mfma_f32_16x16x32_f16(ap, bv, O[dt], 0, 0, 0);
      }
    }
    // ---- store O (C-layout: row n_loc = quad*4+r, col d = dt*16+l15)
#pragma unroll
    for (int dt = 0; dt < 4; dt++)
#pragma unroll
      for (int r = 0; r < 4; r++) {
        const int nrow = nt * 16 + quad * 4 + r;
        if (nrow < NTOK)
          o[((size_t)bt * NTOK + nrow) * D + h * 64 + dt * 16 + l15] =
              (f16)O[dt][r];
      }
  }
}

// ---------------------------------- y = x + scatter(proj_out); yn = LN(y)
__global__ __launch_bounds__(192) void scatter_y_ln(
    const float* __restrict__ x, const f16* __restrict__ po,
    const float* __restrict__ g2, const float* __restrict__ be2,
    float* __restrict__ y, f16* __restrict__ yn) {
  const int rid = blockIdx.x;  // 0..12551
  const int b = rid / SEQ, pos = rid % SEQ;
  const int tid = threadIdx.x, d0 = tid * 4;
  float4 v = *(const float4*)(x + (size_t)rid * D + d0);
  if (pos == 0) {
    float ax = 0, ay = 0, az = 0, aw = 0;
    for (int t = 0; t < 8; t++) {
      const f16x4 p = *(const f16x4*)(po + ((size_t)(b * 8 + t) * NTOK) * D + d0);
      ax += (float)p[0]; ay += (float)p[1]; az += (float)p[2]; aw += (float)p[3];
    }
    v.x += ax * 0.125f; v.y += ay * 0.125f; v.z += az * 0.125f; v.w += aw * 0.125f;
  } else {
    const int hw = (pos - 1) >> 3, t = (pos - 1) & 7;
    const f16x4 p =
        *(const f16x4*)(po + ((size_t)((b * 8 + t) * NTOK + 1 + hw)) * D + d0);
    v.x += (float)p[0]; v.y += (float)p[1]; v.z += (float)p[2]; v.w += (float)p[3];
  }
  *(float4*)(y + (size_t)rid * D + d0) = v;
  float s = v.x + v.y + v.z + v.w;
  float q = v.x * v.x + v.y * v.y + v.z * v.z + v.w * v.w;
  const int lane = tid & 63, wv = tid >> 6;
  for (int off = 32; off; off >>= 1) {
    s += __shfl_xor(s, off);
    q += __shfl_xor(q, off);
  }
  __shared__ float red[2][3];
  if (lane == 0) { red[0][wv] = s; red[1][wv] = q; }
  __syncthreads();
  s = red[0][0] + red[0][1] + red[0][2];
  q = red[1][0] + red[1][1] + red[1][2];
  const float mean = s * (1.f / 768.f);
  const float var = q * (1.f / 768.f) - mean * mean;
  const float rs = rsqrtf(var + 1e-5f);
  const float4 gv = *(const float4*)(g2 + d0);
  const float4 bv = *(const float4*)(be2 + d0);
  f16x4 no = {(f16)((v.x - mean) * rs * gv.x + bv.x),
              (f16)((v.y - mean) * rs * gv.y + bv.y),
              (f16)((v.z - mean) * rs * gv.z + bv.z),
              (f16)((v.w - mean) * rs * gv.w + bv.w)};
  *(f16x4*)(yn + (size_t)rid * D + d0) = no;
}

// ---------------------------------------------------------------- launch
extern "C" void kernel_launch(void* const* d_in, const int* in_sizes, int n_in,
                              void* d_out, int out_size, void* d_ws,
                              size_t ws_size, hipStream_t stream) {
  const float* x = (const float*)d_in[0];
  const float* W_mq = (const float*)d_in[1];
  const float* b_mq = (const float*)d_in[2];
  const float* W_mk = (const float*)d_in[3];
  const float* b_mk = (const float*)d_in[4];
  const float* g1 = (const float*)d_in[5];
  const float* be1 = (const float*)d_in[6];
  const float* W_qkv = (const float*)d_in[7];
  const float* W_proj = (const float*)d_in[8];
  const float* b_proj = (const float*)d_in[9];
  const float* g2 = (const float*)d_in[10];
  const float* be2 = (const float*)d_in[11];
  const float* W_fc1 = (const float*)d_in[12];
  const float* b_fc1 = (const float*)d_in[13];
  const float* W_fc2 = (const float*)d_in[14];
  const float* b_fc2 = (const float*)d_in[15];

  char* ws = (char*)d_ws;
  size_t off = 0;
  auto alloc = [&](size_t bytes) {
    size_t o = off;
    off = (off + bytes + 255) & ~(size_t)255;
    return o;
  };
  const size_t o_wmqk = alloc((size_t)2 * D * D * 2);   // [W_mq; W_mk] stacked
  const size_t o_bmqk = alloc((size_t)2 * D * 4);       // [b_mq; b_mk] f32
  const size_t o_wqkv = alloc((size_t)CW * D * 2);
  const size_t o_wproj = alloc((size_t)D * D * 2);
  const size_t o_wfc1 = alloc((size_t)DH * D * 2);
  const size_t o_wfc2 = alloc((size_t)D * DH * 2);
  const size_t o_xt = alloc((size_t)ROWS_A * D * 2);
  const size_t o_xn = alloc((size_t)ROWS_A * D * 2);
  const size_t o_big = alloc((size_t)ROWS_A * CW * 2);  // qmkm, later qkv
  const size_t o_po = alloc((size_t)ROWS_A * D * 2);
  // aliases (lifetimes disjoint):
  const size_t o_qmkm = o_big;  // ROWS_A x 1536 f16 (38.7 MB < 58 MB)
  const size_t o_qkv = o_big;   // after lm done
  const size_t o_o = o_xn;      // attn out after xn dead
  const size_t o_yn = o_xt;     // yn after xt dead
  const size_t o_h = o_big;     // h (77.4 MB) spans big+po after both dead

  f16* wmqk = (f16*)(ws + o_wmqk);
  float* bmqk = (float*)(ws + o_bmqk);
  f16* wqkv = (f16*)(ws + o_wqkv);
  f16* wproj = (f16*)(ws + o_wproj);
  f16* wfc1 = (f16*)(ws + o_wfc1);
  f16* wfc2 = (f16*)(ws + o_wfc2);
  f16* xt = (f16*)(ws + o_xt);
  f16* xn = (f16*)(ws + o_xn);
  f16* qmkm = (f16*)(ws + o_qmkm);
  f16* qkv = (f16*)(ws + o_qkv);
  f16* oatt = (f16*)(ws + o_o);
  f16* po = (f16*)(ws + o_po);
  f16* yn = (f16*)(ws + o_yn);
  f16* h = (f16*)(ws + o_h);

  float* y_out = (float*)d_out;
  float* lm_out = (float*)d_out + Y_ELEMS;

  const dim3 blk(256);
  cvt_weights<<<dim3((WQ_TOT + 255) / 256), blk, 0, stream>>>(
      W_mq, W_mk, W_qkv, W_proj, W_fc1, W_fc2, wmqk, wqkv, wproj, wfc1, wfc2);
  concat2_f32<<<dim3(6), blk, 0, stream>>>(b_mq, b_mk, bmqk, D);

  build_xt_xn<<<dim3(ROWS_A), dim3(192), 0, stream>>>(x, g1, be1, xt, xn);

  auto grd = [](int N_, int M_, int Z_) {
    return dim3((N_ + 127) / 128, (M_ + 127) / 128, Z_);
  };
  // [qm|km] = xt @ [W_mq;W_mk]^T + [b_mq;b_mk]   (one GEMM, N=1536)
  gemm_f16<EPI_F16_BIAS, true><<<grd(2 * D, ROWS_A, 1), blk, 0, stream>>>(
      xt, wmqk, bmqk, nullptr, qmkm, nullptr, ROWS_A, 2 * D, D, D, D, 2 * D,
      0, 0, 0);
  // lm = sigmoid(qm km^T) batched, straight to d_out (z-batched: no swizzle)
  gemm_f16<EPI_SIG><<<grd(NTOK, NTOK, BT), blk, 0, stream>>>(
      qmkm, qmkm + D, nullptr, lm_out, nullptr, nullptr, NTOK, NTOK, D,
      2 * D, 2 * D, NTOK, (long)NTOK * 2 * D, (long)NTOK * 2 * D,
      (long)NTOK * NTOK);
  // qkv = xn @ W_qkv^T  (no bias)
  gemm_f16<EPI_F16, true><<<grd(CW, ROWS_A, 1), blk, 0, stream>>>(
      xn, wqkv, nullptr, nullptr, qkv, nullptr, ROWS_A, CW, D, D, D, CW,
      0, 0, 0);
  // attention
  attn_kernel<<<dim3(BT * 12), blk, 0, stream>>>(qkv, lm_out, oatt);
  // proj (f16 out + bias)
  gemm_f16<EPI_F16_BIAS, true><<<grd(D, ROWS_A, 1), blk, 0, stream>>>(
      oatt, wproj, b_proj, nullptr, po, nullptr, ROWS_A, D, D, D, D, D,
      0, 0, 0);
  // y = x + scatter(po); yn = LN(y)
  scatter_y_ln<<<dim3(ROWS_Y), dim3(192), 0, stream>>>(x, po, g2, be2, y_out, yn);
  // fc1 + gelu
  gemm_f16<EPI_F16_BIAS_GELU, true><<<grd(DH, ROWS_Y, 1), blk, 0, stream>>>(
      yn, wfc1, b_fc1, nullptr, h, nullptr, ROWS_Y, DH, D, D, D, DH, 0, 0, 0);
  // fc2 + bias + residual -> final y
  gemm_f16<EPI_F32_BIAS_RES, true><<<grd(D, ROWS_Y, 1), blk, 0, stream>>>(
      h, wfc2, b_fc2, y_out, nullptr, y_out, ROWS_Y, D, DH, DH, DH, D,
      0, 0, 0);
  (void)in_sizes; (void)n_in; (void)out_size; (void)ws_size;
}